// Round 22
// baseline (296.529 us; speedup 1.0000x reference)
//
#include <hip/hip_runtime.h>
#include <cstdint>

typedef float  f32x4  __attribute__((ext_vector_type(4)));
typedef float  f32x16 __attribute__((ext_vector_type(16)));
typedef short  short8 __attribute__((ext_vector_type(8)));
typedef _Float16 half4 __attribute__((ext_vector_type(4)));
typedef _Float16 half8 __attribute__((ext_vector_type(8)));
typedef _Float16 half2v __attribute__((ext_vector_type(2)));

// ---------- helpers ----------
__device__ __forceinline__ unsigned short f2bf(float f) {
    unsigned u = __builtin_bit_cast(unsigned, f);
    u += 0x7FFFu + ((u >> 16) & 1u);   // RNE
    return (unsigned short)(u >> 16);
}

__device__ __forceinline__ half2v pkrtz(float a, float b) {
    return __builtin_bit_cast(half2v, __builtin_amdgcn_cvt_pkrtz(a, b));
}

// ---------- kernel 1: weights fp32 -> bf16 (3 x 256 x 256) ----------
__global__ void wconv_kernel(const float* __restrict__ wq,
                             const float* __restrict__ wk,
                             const float* __restrict__ wv,
                             unsigned short* __restrict__ Wb) {
    int p = blockIdx.x >> 8;                       // 0..2
    int i = ((blockIdx.x & 255) << 8) + threadIdx.x; // 0..65535
    const float* src = (p == 0) ? wq : ((p == 1) ? wk : wv);
    Wb[(p << 16) + i] = f2bf(src[i]);
}

// ---------- kernel 2: fused X0-build + QKV projection (R18 structure) ----------
// V global layout (consumed by attn): tile-major 16KB per (b,tt); 16B chunk
// index for V[v][t_in_tile]:  (v<<2) + ((t>>3) ^ ((v>>1)&3)), byte (t&7)*2.
// (R8-verified PV read semantics; attn stages the tile as a contiguous copy.)
__global__ __launch_bounds__(256, 2) void fproj_kernel(
        const float* __restrict__ x,
        const unsigned short* __restrict__ Wb,
        const float* __restrict__ bq, const float* __restrict__ bk,
        const float* __restrict__ bv,
        unsigned short* __restrict__ Q, unsigned short* __restrict__ K,
        _Float16* __restrict__ V) {
    __shared__ __align__(16) char Xlds[32768];   // 64 s-rows x 512B (swz)
    __shared__ __align__(16) char Wlds[32768];   // 64 o-rows x 512B (swz)
    float* Tt = (float*)Wlds;                    // phase-1 scratch [224][33]

    int st = blockIdx.x;            // s-tile 0..15
    int b  = blockIdx.y;            // 0..31
    int sb = st << 6;
    int tid = threadIdx.x; int w = tid >> 6; int l = tid & 63;
    int g = l >> 4, c = l & 15;
    int wr = w >> 1, wc = w & 1;

    // ---- phase 1: build X tile [64s][256c] bf16 in swizzled LDS ----
    #pragma unroll 1
    for (int sc = 0; sc < 2; ++sc) {
        if (sc) __syncthreads();             // protect Tt reuse
        #pragma unroll
        for (int r = 0; r < 28; ++r) {
            int idx = r * 256 + tid;         // 0..7167
            int cc = idx >> 5, lo = idx & 31;
            Tt[cc * 33 + lo] = x[((b * 224 + cc) << 10) + sb + (sc << 5) + lo];
        }
        __syncthreads();
        #pragma unroll
        for (int r = 0; r < 4; ++r) {
            int idx = r * 256 + tid;
            if (idx < 896) {
                int cc16 = idx >> 5;         // 0..27
                int sl = idx & 31;
                int s = (sc << 5) + sl;      // 0..63
                short8 v8;
                #pragma unroll
                for (int j = 0; j < 8; ++j)
                    v8[j] = (short)f2bf(Tt[(cc16 * 8 + j) * 33 + sl]);
                *(short8*)&Xlds[(s << 9) + ((cc16 ^ (s & 7)) << 4)] = v8;
            }
        }
        if (tid < 128) {
            int sl = tid >> 2;
            int cc16 = 28 + (tid & 3);
            int s = (sc << 5) + sl;
            int sg = sb + s;
            int h = sg >> 5, ww = sg & 31;
            short8 v8;
            #pragma unroll
            for (int j = 0; j < 8; ++j) {
                int ch = (cc16 - 28) * 8 + j;        // 0..31
                int i = (ch < 16) ? (ch * 32 + h) : ((ch - 16) * 32 + ww);
                int ll = i >> 4, e = i & 15;
                float val = 0.f;
                if (ll > 0) {
                    float ang = (float)ll * powf(10000.f, -(float)(e >> 1) * 0.125f);
                    val = (e & 1) ? cosf(ang) : sinf(ang);
                }
                v8[j] = (short)f2bf(val);
            }
            *(short8*)&Xlds[(s << 9) + ((cc16 ^ (s & 7)) << 4)] = v8;
        }
    }
    __syncthreads();      // Xlds complete; Tt (Wlds) free

    // ---- hoist A fragments (wave's 32 s-rows) into registers ----
    short8 af[2][8];
    #pragma unroll
    for (int i = 0; i < 2; ++i) {
        const char* ab = &Xlds[(wr * 32 + i * 16 + c) << 9];
        #pragma unroll
        for (int kk = 0; kk < 8; ++kk)
            af[i][kk] = *(const short8*)&ab[((kk * 4 + g) ^ (c & 7)) << 4];
    }

    // ---- phase 2: 12 steps (3 proj x 4 o-tiles of 64), 32KB W stage ----
    #pragma unroll 1
    for (int pj = 0; pj < 3; ++pj) {
        const float* bias = (pj == 0) ? bq : ((pj == 1) ? bk : bv);
        #pragma unroll 1
        for (int ot = 0; ot < 4; ++ot) {
            const unsigned short* Wg = Wb + (pj << 16) + (ot << 14);
            #pragma unroll
            for (int p = 0; p < 8; ++p) {
                int ch = p * 256 + tid;
                int row = ch >> 5;
                int cl = (ch & 31) ^ (row & 7);
                __builtin_amdgcn_global_load_lds(
                    (const unsigned int*)&Wg[(row << 8) + cl * 8],
                    (unsigned int*)(Wlds + ((p << 8) + (w << 6)) * 16), 16, 0, 0);
            }
            asm volatile("s_waitcnt vmcnt(0)\n\ts_barrier" ::: "memory");

            f32x4 acc[2][2];
            #pragma unroll
            for (int i = 0; i < 2; ++i)
                #pragma unroll
                for (int j = 0; j < 2; ++j) acc[i][j] = (f32x4){0.f, 0.f, 0.f, 0.f};

            const char* bb0 = &Wlds[(wc * 32 + c) << 9];
            const char* bb1 = &Wlds[(wc * 32 + 16 + c) << 9];
            __builtin_amdgcn_s_setprio(1);
            #pragma unroll
            for (int kk = 0; kk < 8; ++kk) {
                int co = ((kk * 4 + g) ^ (c & 7)) << 4;
                short8 b0 = *(const short8*)&bb0[co];
                short8 b1 = *(const short8*)&bb1[co];
                acc[0][0] = __builtin_amdgcn_mfma_f32_16x16x32_bf16(af[0][kk], b0, acc[0][0], 0, 0, 0);
                acc[0][1] = __builtin_amdgcn_mfma_f32_16x16x32_bf16(af[0][kk], b1, acc[0][1], 0, 0, 0);
                acc[1][0] = __builtin_amdgcn_mfma_f32_16x16x32_bf16(af[1][kk], b0, acc[1][0], 0, 0, 0);
                acc[1][1] = __builtin_amdgcn_mfma_f32_16x16x32_bf16(af[1][kk], b1, acc[1][1], 0, 0, 0);
            }
            __builtin_amdgcn_s_setprio(0);

            #pragma unroll
            for (int j = 0; j < 2; ++j) {
                int o = (ot << 6) + wc * 32 + j * 16 + c;
                float bbv = bias[o];
                #pragma unroll
                for (int i = 0; i < 2; ++i) {
                    int sgb = sb + wr * 32 + i * 16;
                    if (pj < 2) {
                        unsigned short* dst = (pj == 0) ? Q : K;
                        #pragma unroll
                        for (int r = 0; r < 4; ++r) {
                            float v = fmaxf(acc[i][j][r] + bbv, 0.f);
                            int s = sgb + 4 * g + r;
                            dst[(((b << 10) + s) << 8) + o] = f2bf(v);
                        }
                    } else {
                        half4 hv;
                        #pragma unroll
                        for (int r = 0; r < 4; ++r)
                            hv[r] = (_Float16)fmaxf(acc[i][j][r] + bbv, 0.f);
                        int hi = (sgb >> 4) & 1;     // t_in_tile = hi*16+4g+r
                        int tt = sgb >> 5;
                        int ci = ((hi << 1) | (g >> 1)) ^ ((o >> 1) & 3);
                        *(half4*)&V[((size_t)((b << 5) + tt) << 13)
                                    + ((o << 2) + ci) * 8 + ((g & 1) << 2)] = hv;
                    }
                }
            }
            __syncthreads();    // all waves done reading Wlds before restage
        }
    }
}

// ---------- kernel 3: causal attention, 32x32 MFMA + t-parity split ----------
// 512 blocks x 256 threads. 4 waves = (q-subtile sh) x (t-parity par);
// wave owns 32 q-rows (R8-verified 32x32 math). K/V dbuf LDS, flash-combine
// of parity pairs through the (then-dead) K/V buffers at the end.
__global__ __launch_bounds__(256, 2) void attn_kernel(
        const unsigned short* __restrict__ Q,
        const unsigned short* __restrict__ K,
        const _Float16* __restrict__ V,
        float* __restrict__ out) {
    __shared__ __align__(16) char Klds[2][16384];   // 32 t-rows x 512B
    __shared__ __align__(16) char Vlds[2][16384];   // 1024 chunks x 16B
    __shared__ float cml[2][2][64];                 // [sh][m/l][lane]

    int bid = blockIdx.x;
    int xcd  = bid & 7;
    int qv   = (bid >> 3) & 7;
    int bhi  = (bid >> 6) & 3;
    int hf   = bid >> 8;
    int b  = (bhi << 3) | xcd;
    int qt = hf ? qv : (15 - qv);       // 0..15, 64-row q-tile

    int tid = threadIdx.x; int w = tid >> 6; int l = tid & 63;
    int lo = l >> 5, cs = l & 31;
    int sh = w >> 1, par = w & 1;
    int s0 = (qt << 6) + (sh << 5);     // wave-pair's 32 q-rows
    int sg = s0 + cs;

    // ---- Q fragments (R8 layout: 16 x short8) ----
    short8 qf[16];
    const unsigned short* Qrow = &Q[(((b << 10) + s0 + cs) << 8) + lo * 8];
    #pragma unroll
    for (int kc = 0; kc < 16; ++kc)
        qf[kc] = *(const short8*)&Qrow[kc * 16];

    f32x16 acc[8];
    #pragma unroll
    for (int i = 0; i < 8; ++i)
        #pragma unroll
        for (int r = 0; r < 16; ++r) acc[i][r] = 0.f;
    float m = -1e30f, lsum = 0.f;       // lsum: per-lane partial

    const unsigned short* Kb_ = &K[(size_t)b << 18];
    const _Float16*       Vb_ = &V[(size_t)b << 18];

    int nt = 2 * qt + 2;                // 32-t tiles
    int dtile = 2 * qt + sh;            // this pair's diagonal tile

    auto stage = [&](int t, int bufi) {
        int t0 = t << 5;
        #pragma unroll
        for (int j = 0; j < 4; ++j) {
            int ch = (j << 8) + tid;            // 0..1023
            int trow = ch >> 5;
            int cl = (ch & 31) ^ (trow & 7);
            __builtin_amdgcn_global_load_lds(
                (const unsigned int*)&Kb_[((t0 + trow) << 8) + cl * 8],
                (unsigned int*)(Klds[bufi] + ((j << 8) + (w << 6)) * 16), 16, 0, 0);
        }
        #pragma unroll
        for (int j = 0; j < 4; ++j) {
            int ch = (j << 8) + tid;            // 0..1023
            __builtin_amdgcn_global_load_lds(
                (const unsigned int*)&Vb_[((size_t)t << 13) + ch * 8],
                (unsigned int*)(Vlds[bufi] + ((j << 8) + (w << 6)) * 16), 16, 0, 0);
        }
    };

    stage(0, 0);

    for (int t = 0; t < nt; ++t) {
        asm volatile("s_waitcnt vmcnt(0)\n\ts_barrier" ::: "memory");
        if (t + 1 < nt) stage(t + 1, (t + 1) & 1);   // overlap with compute(t)
        if (((t & 1) != par) || t > dtile) continue; // not my tile; keep cadence

        const char* Kl = Klds[t & 1];
        const char* Vl = Vlds[t & 1];
        int t0 = t << 5;
        // ---- QK^T: D[t][s], 32x32x16, two chains (R8 body) ----
        f32x16 sc0, sc1;
        #pragma unroll
        for (int r = 0; r < 16; ++r) { sc0[r] = 0.f; sc1[r] = 0.f; }
        __builtin_amdgcn_s_setprio(1);
        #pragma unroll
        for (int kc = 0; kc < 16; kc += 2) {
            int p0 = (cs << 5) + (((kc << 1) | lo) ^ (cs & 7));
            int p1 = (cs << 5) + ((((kc + 1) << 1) | lo) ^ (cs & 7));
            short8 a0 = *(const short8*)&Kl[p0 << 4];
            short8 a1 = *(const short8*)&Kl[p1 << 4];
            sc0 = __builtin_amdgcn_mfma_f32_32x32x16_bf16(a0, qf[kc], sc0, 0, 0, 0);
            sc1 = __builtin_amdgcn_mfma_f32_32x32x16_bf16(a1, qf[kc + 1], sc1, 0, 0, 0);
        }
        __builtin_amdgcn_s_setprio(0);
        // ---- scale + diagonal mask ----
        bool diag = (t == dtile);
        float sv[16];
        #pragma unroll
        for (int r = 0; r < 16; ++r) {
            sv[r] = (sc0[r] + sc1[r]) * 0.0625f;
            if (diag) {
                int tg = t0 + (r & 3) + 8 * (r >> 2) + 4 * lo;
                if (tg > sg) sv[r] = -1e30f;
            }
        }
        // ---- softmax: shuffle-free fast path ----
        float tm = sv[0];
        #pragma unroll
        for (int r = 1; r < 16; ++r) tm = fmaxf(tm, sv[r]);
        if (!__all((int)(tm <= m + 8.f))) {
            float tr = fmaxf(tm, __shfl_xor(tm, 32));
            float mnew = fmaxf(m, tr);
            float alpha = __expf(m - mnew);
            m = mnew;
            lsum *= alpha;
            #pragma unroll
            for (int i = 0; i < 8; ++i)
                #pragma unroll
                for (int r = 0; r < 16; ++r) acc[i][r] *= alpha;
        }
        float p[16];
        #pragma unroll
        for (int r = 0; r < 16; ++r) { p[r] = __expf(sv[r] - m); lsum += p[r]; }
        // ---- pack P to f16 pairs (R8 verified) ----
        half2v ph[8];
        #pragma unroll
        for (int i = 0; i < 8; ++i)
            ph[i] = pkrtz(p[2 * i], p[2 * i + 1]);
        // ---- PV, tc = 0 (t 0..15 of tile) ----
        {
            half2v po[4];
            #pragma unroll
            for (int i = 0; i < 4; ++i)
                po[i] = __builtin_bit_cast(half2v,
                    __shfl_xor(__builtin_bit_cast(int, ph[i]), 32));
            half2v e0 = lo ? po[2] : ph[0];
            half2v e1 = lo ? po[3] : ph[1];
            half2v e2 = lo ? ph[2] : po[0];
            half2v e3 = lo ? ph[3] : po[1];
            half8 frag = {e0[0], e0[1], e1[0], e1[1], e2[0], e2[1], e3[0], e3[1]};
            __builtin_amdgcn_s_setprio(1);
            #pragma unroll
            for (int vt = 0; vt < 8; ++vt) {
                int v = (vt << 5) + cs;
                int pos = (v << 2) + (lo ^ ((v >> 1) & 3));
                half8 vf = *(const half8*)&Vl[pos << 4];
                acc[vt] = __builtin_amdgcn_mfma_f32_32x32x16_f16(vf, frag, acc[vt], 0, 0, 0);
            }
            __builtin_amdgcn_s_setprio(0);
        }
        // ---- PV, tc = 1 (t 16..31 of tile) ----
        {
            half2v po[4];
            #pragma unroll
            for (int i = 0; i < 4; ++i)
                po[i] = __builtin_bit_cast(half2v,
                    __shfl_xor(__builtin_bit_cast(int, ph[4 + i]), 32));
            half2v e0 = lo ? po[2] : ph[4];
            half2v e1 = lo ? po[3] : ph[5];
            half2v e2 = lo ? ph[6] : po[0];
            half2v e3 = lo ? ph[7] : po[1];
            half8 frag = {e0[0], e0[1], e1[0], e1[1], e2[0], e2[1], e3[0], e3[1]};
            __builtin_amdgcn_s_setprio(1);
            #pragma unroll
            for (int vt = 0; vt < 8; ++vt) {
                int v = (vt << 5) + cs;
                int pos = (v << 2) + ((2 | lo) ^ ((v >> 1) & 3));
                half8 vf = *(const half8*)&Vl[pos << 4];
                acc[vt] = __builtin_amdgcn_mfma_f32_32x32x16_f16(vf, frag, acc[vt], 0, 0, 0);
            }
            __builtin_amdgcn_s_setprio(0);
        }
    }

    // ---- flash combine: parity pairs through dead K/V LDS ----
    __syncthreads();
    float* cb = sh ? (float*)Vlds : (float*)Klds;   // 32KB per pair
    if (par == 1) {
        #pragma unroll
        for (int i = 0; i < 8; ++i)
            #pragma unroll
            for (int r = 0; r < 16; ++r)
                cb[((i * 16 + r) << 6) + l] = acc[i][r];
        cml[sh][0][l] = m;
        cml[sh][1][l] = lsum;
    }
    __syncthreads();
    if (par == 0) {
        float m1 = cml[sh][0][l];
        float l1 = cml[sh][1][l];
        float ms = fmaxf(m, m1);
        float a0 = __expf(m - ms);
        float a1 = __expf(m1 - ms);
        float lt = lsum * a0 + l1 * a1;
        lt += __shfl_xor(lt, 32);
        float rl = 1.f / lt;
        #pragma unroll
        for (int i = 0; i < 8; ++i) {
            #pragma unroll
            for (int r = 0; r < 16; ++r) {
                float vv = (acc[i][r] * a0 + cb[((i * 16 + r) << 6) + l] * a1) * rl;
                int vrow = (i << 5) + (r & 3) + 8 * (r >> 2) + 4 * lo;
                out[(((b << 8) + vrow) << 10) + sg] = vv;
            }
        }
    }
}

// ---------- launcher ----------
extern "C" void kernel_launch(void* const* d_in, const int* in_sizes, int n_in,
                              void* d_out, int out_size, void* d_ws, size_t ws_size,
                              hipStream_t stream) {
    const float* x  = (const float*)d_in[0];
    const float* wq = (const float*)d_in[1];
    const float* bq = (const float*)d_in[2];
    const float* wk = (const float*)d_in[3];
    const float* bk = (const float*)d_in[4];
    const float* wv = (const float*)d_in[5];
    const float* bv = (const float*)d_in[6];
    float* out = (float*)d_out;

    char* ws = (char*)d_ws;
    unsigned short* Wb = (unsigned short*)ws;                       // 393,216 B
    unsigned short* Qb = (unsigned short*)(ws + 393216);
    unsigned short* Kb = (unsigned short*)(ws + 393216 + 16777216);
    _Float16*       Vb = (_Float16*)     (ws + 393216 + 2 * 16777216);

    wconv_kernel<<<768, 256, 0, stream>>>(wq, wk, wv, Wb);
    fproj_kernel<<<dim3(16, 32), 256, 0, stream>>>(x, Wb, bq, bk, bv, Qb, Kb, Vb);
    attn_kernel<<<512, 256, 0, stream>>>(Qb, Kb, Vb, out);
}

// Round 23
// 99.808 us; speedup vs baseline: 2.9710x; 2.9710x over previous
//
#include <hip/hip_runtime.h>
#include <cstdint>

typedef float  f32x4  __attribute__((ext_vector_type(4)));
typedef short  short8 __attribute__((ext_vector_type(8)));
typedef _Float16 half4 __attribute__((ext_vector_type(4)));
typedef _Float16 half8 __attribute__((ext_vector_type(8)));

// ---------- helpers ----------
__device__ __forceinline__ unsigned short f2bf(float f) {
    unsigned u = __builtin_bit_cast(unsigned, f);
    u += 0x7FFFu + ((u >> 16) & 1u);   // RNE
    return (unsigned short)(u >> 16);
}

// ---------- kernel 1: weights fp32 -> bf16 (3 x 256 x 256) ----------
__global__ void wconv_kernel(const float* __restrict__ wq,
                             const float* __restrict__ wk,
                             const float* __restrict__ wv,
                             unsigned short* __restrict__ Wb) {
    int p = blockIdx.x >> 8;                       // 0..2
    int i = ((blockIdx.x & 255) << 8) + threadIdx.x; // 0..65535
    const float* src = (p == 0) ? wq : ((p == 1) ? wk : wv);
    Wb[(p << 16) + i] = f2bf(src[i]);
}

// ---------- kernel 2: fused X0-build + QKV projection (R18, best) ----------
// V global layout (consumed by attn): tile-major with BAKED chunk swizzle:
// V[b][tt] is a 16KB tile of 1024 16B chunks; row v chunk g lives at chunk
// index 4v + (g ^ ((v>>1)&3)). attn stages it as a pure contiguous copy.
__global__ __launch_bounds__(256, 2) void fproj_kernel(
        const float* __restrict__ x,
        const unsigned short* __restrict__ Wb,
        const float* __restrict__ bq, const float* __restrict__ bk,
        const float* __restrict__ bv,
        unsigned short* __restrict__ Q, unsigned short* __restrict__ K,
        _Float16* __restrict__ V) {
    __shared__ __align__(16) char Xlds[32768];   // 64 s-rows x 512B (swz)
    __shared__ __align__(16) char Wlds[32768];   // 64 o-rows x 512B (swz)
    float* Tt = (float*)Wlds;                    // phase-1 scratch [224][33]

    int st = blockIdx.x;            // s-tile 0..15
    int b  = blockIdx.y;            // 0..31
    int sb = st << 6;
    int tid = threadIdx.x; int w = tid >> 6; int l = tid & 63;
    int g = l >> 4, c = l & 15;
    int wr = w >> 1, wc = w & 1;

    // ---- phase 1: build X tile [64s][256c] bf16 in swizzled LDS ----
    #pragma unroll 1
    for (int sc = 0; sc < 2; ++sc) {
        if (sc) __syncthreads();             // protect Tt reuse
        #pragma unroll
        for (int r = 0; r < 28; ++r) {
            int idx = r * 256 + tid;         // 0..7167
            int cc = idx >> 5, lo = idx & 31;
            Tt[cc * 33 + lo] = x[((b * 224 + cc) << 10) + sb + (sc << 5) + lo];
        }
        __syncthreads();
        #pragma unroll
        for (int r = 0; r < 4; ++r) {
            int idx = r * 256 + tid;
            if (idx < 896) {
                int cc16 = idx >> 5;         // 0..27
                int sl = idx & 31;
                int s = (sc << 5) + sl;      // 0..63
                short8 v8;
                #pragma unroll
                for (int j = 0; j < 8; ++j)
                    v8[j] = (short)f2bf(Tt[(cc16 * 8 + j) * 33 + sl]);
                *(short8*)&Xlds[(s << 9) + ((cc16 ^ (s & 7)) << 4)] = v8;
            }
        }
        if (tid < 128) {
            int sl = tid >> 2;
            int cc16 = 28 + (tid & 3);
            int s = (sc << 5) + sl;
            int sg = sb + s;
            int h = sg >> 5, ww = sg & 31;
            short8 v8;
            #pragma unroll
            for (int j = 0; j < 8; ++j) {
                int ch = (cc16 - 28) * 8 + j;        // 0..31
                int i = (ch < 16) ? (ch * 32 + h) : ((ch - 16) * 32 + ww);
                int ll = i >> 4, e = i & 15;
                float val = 0.f;
                if (ll > 0) {
                    float ang = (float)ll * powf(10000.f, -(float)(e >> 1) * 0.125f);
                    val = (e & 1) ? cosf(ang) : sinf(ang);
                }
                v8[j] = (short)f2bf(val);
            }
            *(short8*)&Xlds[(s << 9) + ((cc16 ^ (s & 7)) << 4)] = v8;
        }
    }
    __syncthreads();      // Xlds complete; Tt (Wlds) free

    // ---- hoist A fragments (wave's 32 s-rows) into registers ----
    short8 af[2][8];
    #pragma unroll
    for (int i = 0; i < 2; ++i) {
        const char* ab = &Xlds[(wr * 32 + i * 16 + c) << 9];
        #pragma unroll
        for (int kk = 0; kk < 8; ++kk)
            af[i][kk] = *(const short8*)&ab[((kk * 4 + g) ^ (c & 7)) << 4];
    }

    // ---- phase 2: 12 steps (3 proj x 4 o-tiles of 64), 32KB W stage ----
    #pragma unroll 1
    for (int pj = 0; pj < 3; ++pj) {
        const float* bias = (pj == 0) ? bq : ((pj == 1) ? bk : bv);
        #pragma unroll 1
        for (int ot = 0; ot < 4; ++ot) {
            const unsigned short* Wg = Wb + (pj << 16) + (ot << 14);
            #pragma unroll
            for (int p = 0; p < 8; ++p) {
                int ch = p * 256 + tid;
                int row = ch >> 5;
                int cl = (ch & 31) ^ (row & 7);
                __builtin_amdgcn_global_load_lds(
                    (const unsigned int*)&Wg[(row << 8) + cl * 8],
                    (unsigned int*)(Wlds + ((p << 8) + (w << 6)) * 16), 16, 0, 0);
            }
            asm volatile("s_waitcnt vmcnt(0)\n\ts_barrier" ::: "memory");

            f32x4 acc[2][2];
            #pragma unroll
            for (int i = 0; i < 2; ++i)
                #pragma unroll
                for (int j = 0; j < 2; ++j) acc[i][j] = (f32x4){0.f, 0.f, 0.f, 0.f};

            const char* bb0 = &Wlds[(wc * 32 + c) << 9];
            const char* bb1 = &Wlds[(wc * 32 + 16 + c) << 9];
            __builtin_amdgcn_s_setprio(1);
            #pragma unroll
            for (int kk = 0; kk < 8; ++kk) {
                int co = ((kk * 4 + g) ^ (c & 7)) << 4;
                short8 b0 = *(const short8*)&bb0[co];
                short8 b1 = *(const short8*)&bb1[co];
                acc[0][0] = __builtin_amdgcn_mfma_f32_16x16x32_bf16(af[0][kk], b0, acc[0][0], 0, 0, 0);
                acc[0][1] = __builtin_amdgcn_mfma_f32_16x16x32_bf16(af[0][kk], b1, acc[0][1], 0, 0, 0);
                acc[1][0] = __builtin_amdgcn_mfma_f32_16x16x32_bf16(af[1][kk], b0, acc[1][0], 0, 0, 0);
                acc[1][1] = __builtin_amdgcn_mfma_f32_16x16x32_bf16(af[1][kk], b1, acc[1][1], 0, 0, 0);
            }
            __builtin_amdgcn_s_setprio(0);

            #pragma unroll
            for (int j = 0; j < 2; ++j) {
                int o = (ot << 6) + wc * 32 + j * 16 + c;
                float bbv = bias[o];
                #pragma unroll
                for (int i = 0; i < 2; ++i) {
                    int sgb = sb + wr * 32 + i * 16;
                    if (pj < 2) {
                        unsigned short* dst = (pj == 0) ? Q : K;
                        #pragma unroll
                        for (int r = 0; r < 4; ++r) {
                            float v = fmaxf(acc[i][j][r] + bbv, 0.f);
                            int s = sgb + 4 * g + r;
                            dst[(((b << 10) + s) << 8) + o] = f2bf(v);
                        }
                    } else {
                        half4 hv;
                        #pragma unroll
                        for (int r = 0; r < 4; ++r)
                            hv[r] = (_Float16)fmaxf(acc[i][j][r] + bbv, 0.f);
                        int hi = (sgb >> 4) & 1;
                        int tt = sgb >> 5;
                        *(half4*)&V[((size_t)((b << 5) + tt) << 13)
                                    + ((o << 2) + (g ^ ((o >> 1) & 3))) * 8
                                    + (hi << 2)] = hv;
                    }
                }
            }
            __syncthreads();    // all waves done reading Wlds before restage
        }
    }
}

// ---------- kernel 3: causal attention (R17/R18, best: 56 us) ----------
__global__ __launch_bounds__(256, 2) void attn_kernel(
        const unsigned short* __restrict__ Q,
        const unsigned short* __restrict__ K,
        const _Float16* __restrict__ V,
        float* __restrict__ out) {
    __shared__ __align__(16) char Klds[2][16384];   // 32 t-rows x 512B
    __shared__ __align__(16) char Vlds[2][16384];   // 1024 chunks x 16B

    int bid = blockIdx.x;
    int xcd  = bid & 7;
    int qv   = (bid >> 3) & 7;
    int bhi  = (bid >> 6) & 3;
    int hf   = bid >> 8;
    int b  = (bhi << 3) | xcd;
    int qt = hf ? qv : (15 - qv);       // 0..15, 64-row q-tile

    int tid = threadIdx.x; int w = tid >> 6; int l = tid & 63;
    int g = l >> 4, c = l & 15;
    int s0 = (qt << 6) + (w << 4);      // this wave's 16 q-rows

    // ---- Q fragments ----
    short8 qf[8];
    #pragma unroll
    for (int kk = 0; kk < 8; ++kk)
        qf[kk] = *(const short8*)&Q[(((b << 10) + s0 + c) << 8) + kk * 32 + g * 8];

    float m = -1e30f, lsum = 0.f;       // lsum: per-lane partial
    f32x4 acc[16];
    #pragma unroll
    for (int i = 0; i < 16; ++i) acc[i] = (f32x4){0.f, 0.f, 0.f, 0.f};

    const unsigned short* Kb_ = &K[(size_t)b << 18];
    const _Float16*       Vb_ = &V[(size_t)b << 18];

    int nt = 2 * qt + 2;                // 32-wide t-tiles
    int dt = 2 * qt + (w >> 1);         // this wave's diagonal t-tile

    auto stage = [&](int t, int bufi) {
        int t0 = t << 5;
        #pragma unroll
        for (int j = 0; j < 4; ++j) {
            int ch = (j << 8) + tid;            // 0..1023
            int trow = ch >> 5;
            int cl = (ch & 31) ^ (trow & 7);
            __builtin_amdgcn_global_load_lds(
                (const unsigned int*)&Kb_[((t0 + trow) << 8) + cl * 8],
                (unsigned int*)(Klds[bufi] + ((j << 8) + (w << 6)) * 16), 16, 0, 0);
        }
        // V tile: contiguous 16KB copy (swizzle pre-baked by fproj)
        #pragma unroll
        for (int j = 0; j < 4; ++j) {
            int ch = (j << 8) + tid;            // 0..1023
            __builtin_amdgcn_global_load_lds(
                (const unsigned int*)&Vb_[((size_t)t << 13) + ch * 8],
                (unsigned int*)(Vlds[bufi] + ((j << 8) + (w << 6)) * 16), 16, 0, 0);
        }
    };

    stage(0, 0);

    for (int t = 0; t < nt; ++t) {
        asm volatile("s_waitcnt vmcnt(0)\n\ts_barrier" ::: "memory");
        if (t + 1 < nt) stage(t + 1, (t + 1) & 1);   // overlap with compute(t)
        if (t > dt) continue;                        // done; keep barrier cadence

        const char* Kl = Klds[t & 1];
        const char* Vl = Vlds[t & 1];
        // ---- V fragments: one conflict-free b128 per vt (both subs) ----
        half8 vread[16];
        #pragma unroll
        for (int vt = 0; vt < 16; ++vt) {
            int pos = (vt << 6) + (c << 2) + (g ^ ((c >> 1) & 3));
            vread[vt] = *(const half8*)&Vl[pos << 4];
        }
        #pragma unroll
        for (int sub = 0; sub < 2; ++sub) {
            bool dmask = (t == dt) && (sub == (w & 1));
            if ((t == dt) && !(w & 1) && sub == 1) break;   // fully above diag
            int toff = sub << 4;
            // ---- QK^T from LDS (16x16x32, 2 chains) ----
            f32x4 sc0 = {0.f,0.f,0.f,0.f}, sc1 = {0.f,0.f,0.f,0.f};
            const char* kbase = &Kl[(toff + c) * 512];
            __builtin_amdgcn_s_setprio(1);
            #pragma unroll
            for (int kk = 0; kk < 8; kk += 2) {
                short8 a0 = *(const short8*)&kbase[(((kk * 4 + g)       ^ (c & 7)) << 4)];
                short8 a1 = *(const short8*)&kbase[((((kk + 1) * 4 + g) ^ (c & 7)) << 4)];
                sc0 = __builtin_amdgcn_mfma_f32_16x16x32_bf16(a0, qf[kk], sc0, 0, 0, 0);
                sc1 = __builtin_amdgcn_mfma_f32_16x16x32_bf16(a1, qf[kk + 1], sc1, 0, 0, 0);
            }
            __builtin_amdgcn_s_setprio(0);
            // ---- scale + diagonal mask ----
            float sv[4];
            #pragma unroll
            for (int r = 0; r < 4; ++r) sv[r] = (sc0[r] + sc1[r]) * 0.0625f;
            if (dmask) {
                #pragma unroll
                for (int r = 0; r < 4; ++r)
                    if (4 * g + r > c) sv[r] = -1e30f;
            }
            // ---- softmax: shuffle-free fast path ----
            float tm = fmaxf(fmaxf(sv[0], sv[1]), fmaxf(sv[2], sv[3]));
            if (!__all((int)(tm <= m + 8.f))) {          // rare slow path
                float tr = fmaxf(tm, __shfl_xor(tm, 16));
                tr = fmaxf(tr, __shfl_xor(tr, 32));
                float mnew = fmaxf(m, tr);
                float alpha = __expf(m - mnew);
                m = mnew;
                lsum *= alpha;
                #pragma unroll
                for (int i = 0; i < 16; ++i) acc[i] *= alpha;
            }
            float p[4];
            #pragma unroll
            for (int r = 0; r < 4; ++r) { p[r] = __expf(sv[r] - m); lsum += p[r]; }
            half4 pb;
            #pragma unroll
            for (int r = 0; r < 4; ++r) pb[r] = (_Float16)p[r];
            // ---- PV (16x16x16 f16) ----
            __builtin_amdgcn_s_setprio(1);
            #pragma unroll
            for (int vt = 0; vt < 16; ++vt) {
                half4 vf;
                #pragma unroll
                for (int jj = 0; jj < 4; ++jj) vf[jj] = vread[vt][sub * 4 + jj];
                acc[vt] = __builtin_amdgcn_mfma_f32_16x16x16f16(vf, pb, acc[vt], 0, 0, 0);
            }
            __builtin_amdgcn_s_setprio(0);
        }
    }

    // ---- epilogue: row-sum of lsum (only softmax shuffles), write ----
    lsum += __shfl_xor(lsum, 16);
    lsum += __shfl_xor(lsum, 32);
    float rl = 1.f / lsum;
    #pragma unroll
    for (int vt = 0; vt < 16; ++vt) {
        #pragma unroll
        for (int r = 0; r < 4; ++r)
            out[(((b << 8) + vt * 16 + 4 * g + r) << 10) + s0 + c] = acc[vt][r] * rl;
    }
}

// ---------- launcher ----------
extern "C" void kernel_launch(void* const* d_in, const int* in_sizes, int n_in,
                              void* d_out, int out_size, void* d_ws, size_t ws_size,
                              hipStream_t stream) {
    const float* x  = (const float*)d_in[0];
    const float* wq = (const float*)d_in[1];
    const float* bq = (const float*)d_in[2];
    const float* wk = (const float*)d_in[3];
    const float* bk = (const float*)d_in[4];
    const float* wv = (const float*)d_in[5];
    const float* bv = (const float*)d_in[6];
    float* out = (float*)d_out;

    char* ws = (char*)d_ws;
    unsigned short* Wb = (unsigned short*)ws;                       // 393,216 B
    unsigned short* Qb = (unsigned short*)(ws + 393216);
    unsigned short* Kb = (unsigned short*)(ws + 393216 + 16777216);
    _Float16*       Vb = (_Float16*)     (ws + 393216 + 2 * 16777216);

    wconv_kernel<<<768, 256, 0, stream>>>(wq, wk, wv, Wb);
    fproj_kernel<<<dim3(16, 32), 256, 0, stream>>>(x, Wb, bq, bk, bv, Qb, Kb, Vb);
    attn_kernel<<<512, 256, 0, stream>>>(Qb, Kb, Vb, out);
}

// Round 25
// 91.595 us; speedup vs baseline: 3.2374x; 1.0897x over previous
//
#include <hip/hip_runtime.h>
#include <cstdint>

typedef float  f32x4  __attribute__((ext_vector_type(4)));
typedef short  short8 __attribute__((ext_vector_type(8)));
typedef _Float16 half4 __attribute__((ext_vector_type(4)));
typedef _Float16 half8 __attribute__((ext_vector_type(8)));

// ---------- helpers ----------
__device__ __forceinline__ unsigned short f2bf(float f) {
    unsigned u = __builtin_bit_cast(unsigned, f);
    u += 0x7FFFu + ((u >> 16) & 1u);   // RNE
    return (unsigned short)(u >> 16);
}

// ---------- kernel 1: weights fp32 -> bf16 + PE table ----------
// blocks 0..767: weight convert. block 768: 512-entry pos-enc table
// pe[i], i = l*16+e: l>0 ? (e odd ? cos : sin)(l * 10000^(-(e/2)/8)) : 0
__global__ void wconv_kernel(const float* __restrict__ wq,
                             const float* __restrict__ wk,
                             const float* __restrict__ wv,
                             unsigned short* __restrict__ Wb,
                             unsigned short* __restrict__ PE) {
    if (blockIdx.x == 768) {
        for (int i = threadIdx.x; i < 512; i += 256) {   // 256 threads, 512 entries
            int l = i >> 4, e = i & 15;
            float val = 0.f;
            if (l > 0) {
                float ang = (float)l * powf(10000.f, -(float)(e >> 1) * 0.125f);
                val = (e & 1) ? cosf(ang) : sinf(ang);
            }
            PE[i] = f2bf(val);
        }
        return;
    }
    int p = blockIdx.x >> 8;                       // 0..2
    int i = ((blockIdx.x & 255) << 8) + threadIdx.x; // 0..65535
    const float* src = (p == 0) ? wq : ((p == 1) ? wk : wv);
    Wb[(p << 16) + i] = f2bf(src[i]);
}

// ---------- kernel 2: fused X0-build + QKV projection ----------
// Phase 1: x chunk staged via global_load_lds into linear Tt (f32), then
// transposed/converted into swizzled Xlds; pos-enc channels from PE table.
// Phase 2 (R18 best): 12 steps, 32KB W stage, 2x2 16x16 MFMA per wave.
// V global layout: tile-major baked swizzle (16KB/tile, chunk 4v+(g^((v>>1)&3))).
__global__ __launch_bounds__(256, 2) void fproj_kernel(
        const float* __restrict__ x,
        const unsigned short* __restrict__ Wb,
        const unsigned short* __restrict__ PE,
        const float* __restrict__ bq, const float* __restrict__ bk,
        const float* __restrict__ bv,
        unsigned short* __restrict__ Q, unsigned short* __restrict__ K,
        _Float16* __restrict__ V) {
    __shared__ __align__(16) char Xlds[32768];   // 64 s-rows x 512B (swz)
    __shared__ __align__(16) char Wlds[32768];   // 64 o-rows x 512B (swz)
    float* Tt = (float*)Wlds;                    // phase-1 scratch [224][32] linear

    int st = blockIdx.x;            // s-tile 0..15
    int b  = blockIdx.y;            // 0..31
    int sb = st << 6;
    int tid = threadIdx.x; int w = tid >> 6; int l = tid & 63;
    int g = l >> 4, c = l & 15;
    int wr = w >> 1, wc = w & 1;

    // ---- phase 1: build X tile [64s][256c] bf16 in swizzled LDS ----
    #pragma unroll 1
    for (int sc = 0; sc < 2; ++sc) {
        if (sc) __syncthreads();             // protect Tt reuse
        // stage x chunk (224 rows x 32 cols f32) via glds, linear dest
        #pragma unroll
        for (int j = 0; j < 7; ++j) {
            int ch = j * 256 + tid;          // 0..1791 (16B chunks)
            int row = ch >> 3, c4 = ch & 7;
            __builtin_amdgcn_global_load_lds(
                (const unsigned int*)&x[((b * 224 + row) << 10) + sb + (sc << 5) + (c4 << 2)],
                (unsigned int*)((char*)Tt + ((j << 8) + (w << 6)) * 16), 16, 0, 0);
        }
        asm volatile("s_waitcnt vmcnt(0)\n\ts_barrier" ::: "memory");
        // emit transposed bf16 16B chunks (c 0..223)
        #pragma unroll
        for (int r = 0; r < 4; ++r) {
            int idx = r * 256 + tid;
            if (idx < 896) {
                int cc16 = idx >> 5;         // 0..27
                int sl = idx & 31;
                int s = (sc << 5) + sl;      // 0..63
                short8 v8;
                #pragma unroll
                for (int j = 0; j < 8; ++j)
                    v8[j] = (short)f2bf(Tt[(cc16 * 8 + j) * 32 + sl]);
                *(short8*)&Xlds[(s << 9) + ((cc16 ^ (s & 7)) << 4)] = v8;
            }
        }
        // pos-enc chunks (c 224..255) from precomputed table
        if (tid < 128) {
            int sl = tid >> 2;
            int cc16 = 28 + (tid & 3);
            int s = (sc << 5) + sl;
            int sg = sb + s;
            int h = sg >> 5, ww = sg & 31;
            short8 v8;
            #pragma unroll
            for (int j = 0; j < 8; ++j) {
                int ch = (cc16 - 28) * 8 + j;        // 0..31
                int i = (ch < 16) ? (ch * 32 + h) : ((ch - 16) * 32 + ww);
                v8[j] = (short)PE[i];
            }
            *(short8*)&Xlds[(s << 9) + ((cc16 ^ (s & 7)) << 4)] = v8;
        }
    }
    __syncthreads();      // Xlds complete; Tt (Wlds) free

    // ---- hoist A fragments (wave's 32 s-rows) into registers ----
    short8 af[2][8];
    #pragma unroll
    for (int i = 0; i < 2; ++i) {
        const char* ab = &Xlds[(wr * 32 + i * 16 + c) << 9];
        #pragma unroll
        for (int kk = 0; kk < 8; ++kk)
            af[i][kk] = *(const short8*)&ab[((kk * 4 + g) ^ (c & 7)) << 4];
    }

    // ---- phase 2: 12 steps (3 proj x 4 o-tiles of 64), 32KB W stage ----
    #pragma unroll 1
    for (int pj = 0; pj < 3; ++pj) {
        const float* bias = (pj == 0) ? bq : ((pj == 1) ? bk : bv);
        #pragma unroll 1
        for (int ot = 0; ot < 4; ++ot) {
            const unsigned short* Wg = Wb + (pj << 16) + (ot << 14);
            #pragma unroll
            for (int p = 0; p < 8; ++p) {
                int ch = p * 256 + tid;
                int row = ch >> 5;
                int cl = (ch & 31) ^ (row & 7);
                __builtin_amdgcn_global_load_lds(
                    (const unsigned int*)&Wg[(row << 8) + cl * 8],
                    (unsigned int*)(Wlds + ((p << 8) + (w << 6)) * 16), 16, 0, 0);
            }
            asm volatile("s_waitcnt vmcnt(0)\n\ts_barrier" ::: "memory");

            f32x4 acc[2][2];
            #pragma unroll
            for (int i = 0; i < 2; ++i)
                #pragma unroll
                for (int j = 0; j < 2; ++j) acc[i][j] = (f32x4){0.f, 0.f, 0.f, 0.f};

            const char* bb0 = &Wlds[(wc * 32 + c) << 9];
            const char* bb1 = &Wlds[(wc * 32 + 16 + c) << 9];
            __builtin_amdgcn_s_setprio(1);
            #pragma unroll
            for (int kk = 0; kk < 8; ++kk) {
                int co = ((kk * 4 + g) ^ (c & 7)) << 4;
                short8 b0 = *(const short8*)&bb0[co];
                short8 b1 = *(const short8*)&bb1[co];
                acc[0][0] = __builtin_amdgcn_mfma_f32_16x16x32_bf16(af[0][kk], b0, acc[0][0], 0, 0, 0);
                acc[0][1] = __builtin_amdgcn_mfma_f32_16x16x32_bf16(af[0][kk], b1, acc[0][1], 0, 0, 0);
                acc[1][0] = __builtin_amdgcn_mfma_f32_16x16x32_bf16(af[1][kk], b0, acc[1][0], 0, 0, 0);
                acc[1][1] = __builtin_amdgcn_mfma_f32_16x16x32_bf16(af[1][kk], b1, acc[1][1], 0, 0, 0);
            }
            __builtin_amdgcn_s_setprio(0);

            #pragma unroll
            for (int j = 0; j < 2; ++j) {
                int o = (ot << 6) + wc * 32 + j * 16 + c;
                float bbv = bias[o];
                #pragma unroll
                for (int i = 0; i < 2; ++i) {
                    int sgb = sb + wr * 32 + i * 16;
                    if (pj < 2) {
                        unsigned short* dst = (pj == 0) ? Q : K;
                        #pragma unroll
                        for (int r = 0; r < 4; ++r) {
                            float v = fmaxf(acc[i][j][r] + bbv, 0.f);
                            int s = sgb + 4 * g + r;
                            dst[(((b << 10) + s) << 8) + o] = f2bf(v);
                        }
                    } else {
                        half4 hv;
                        #pragma unroll
                        for (int r = 0; r < 4; ++r)
                            hv[r] = (_Float16)fmaxf(acc[i][j][r] + bbv, 0.f);
                        int hi = (sgb >> 4) & 1;
                        int tt = sgb >> 5;
                        *(half4*)&V[((size_t)((b << 5) + tt) << 13)
                                    + ((o << 2) + (g ^ ((o >> 1) & 3))) * 8
                                    + (hi << 2)] = hv;
                    }
                }
            }
            __syncthreads();    // all waves done reading Wlds before restage
        }
    }
}

// ---------- kernel 3: causal attention (R17/R18, best: 56 us) ----------
__global__ __launch_bounds__(256, 2) void attn_kernel(
        const unsigned short* __restrict__ Q,
        const unsigned short* __restrict__ K,
        const _Float16* __restrict__ V,
        float* __restrict__ out) {
    __shared__ __align__(16) char Klds[2][16384];   // 32 t-rows x 512B
    __shared__ __align__(16) char Vlds[2][16384];   // 1024 chunks x 16B

    int bid = blockIdx.x;
    int xcd  = bid & 7;
    int qv   = (bid >> 3) & 7;
    int bhi  = (bid >> 6) & 3;
    int hf   = bid >> 8;
    int b  = (bhi << 3) | xcd;
    int qt = hf ? qv : (15 - qv);       // 0..15, 64-row q-tile

    int tid = threadIdx.x; int w = tid >> 6; int l = tid & 63;
    int g = l >> 4, c = l & 15;
    int s0 = (qt << 6) + (w << 4);      // this wave's 16 q-rows

    // ---- Q fragments ----
    short8 qf[8];
    #pragma unroll
    for (int kk = 0; kk < 8; ++kk)
        qf[kk] = *(const short8*)&Q[(((b << 10) + s0 + c) << 8) + kk * 32 + g * 8];

    float m = -1e30f, lsum = 0.f;       // lsum: per-lane partial
    f32x4 acc[16];
    #pragma unroll
    for (int i = 0; i < 16; ++i) acc[i] = (f32x4){0.f, 0.f, 0.f, 0.f};

    const unsigned short* Kb_ = &K[(size_t)b << 18];
    const _Float16*       Vb_ = &V[(size_t)b << 18];

    int nt = 2 * qt + 2;                // 32-wide t-tiles
    int dt = 2 * qt + (w >> 1);         // this wave's diagonal t-tile

    auto stage = [&](int t, int bufi) {
        int t0 = t << 5;
        #pragma unroll
        for (int j = 0; j < 4; ++j) {
            int ch = (j << 8) + tid;            // 0..1023
            int trow = ch >> 5;
            int cl = (ch & 31) ^ (trow & 7);
            __builtin_amdgcn_global_load_lds(
                (const unsigned int*)&Kb_[((t0 + trow) << 8) + cl * 8],
                (unsigned int*)(Klds[bufi] + ((j << 8) + (w << 6)) * 16), 16, 0, 0);
        }
        // V tile: contiguous 16KB copy (swizzle pre-baked by fproj)
        #pragma unroll
        for (int j = 0; j < 4; ++j) {
            int ch = (j << 8) + tid;            // 0..1023
            __builtin_amdgcn_global_load_lds(
                (const unsigned int*)&Vb_[((size_t)t << 13) + ch * 8],
                (unsigned int*)(Vlds[bufi] + ((j << 8) + (w << 6)) * 16), 16, 0, 0);
        }
    };

    stage(0, 0);

    for (int t = 0; t < nt; ++t) {
        asm volatile("s_waitcnt vmcnt(0)\n\ts_barrier" ::: "memory");
        if (t + 1 < nt) stage(t + 1, (t + 1) & 1);   // overlap with compute(t)
        if (t > dt) continue;                        // done; keep barrier cadence

        const char* Kl = Klds[t & 1];
        const char* Vl = Vlds[t & 1];
        // ---- V fragments: one conflict-free b128 per vt (both subs) ----
        half8 vread[16];
        #pragma unroll
        for (int vt = 0; vt < 16; ++vt) {
            int pos = (vt << 6) + (c << 2) + (g ^ ((c >> 1) & 3));
            vread[vt] = *(const half8*)&Vl[pos << 4];
        }
        #pragma unroll
        for (int sub = 0; sub < 2; ++sub) {
            bool dmask = (t == dt) && (sub == (w & 1));
            if ((t == dt) && !(w & 1) && sub == 1) break;   // fully above diag
            int toff = sub << 4;
            // ---- QK^T from LDS (16x16x32, 2 chains) ----
            f32x4 sc0 = {0.f,0.f,0.f,0.f}, sc1 = {0.f,0.f,0.f,0.f};
            const char* kbase = &Kl[(toff + c) * 512];
            __builtin_amdgcn_s_setprio(1);
            #pragma unroll
            for (int kk = 0; kk < 8; kk += 2) {
                short8 a0 = *(const short8*)&kbase[(((kk * 4 + g)       ^ (c & 7)) << 4)];
                short8 a1 = *(const short8*)&kbase[((((kk + 1) * 4 + g) ^ (c & 7)) << 4)];
                sc0 = __builtin_amdgcn_mfma_f32_16x16x32_bf16(a0, qf[kk], sc0, 0, 0, 0);
                sc1 = __builtin_amdgcn_mfma_f32_16x16x32_bf16(a1, qf[kk + 1], sc1, 0, 0, 0);
            }
            __builtin_amdgcn_s_setprio(0);
            // ---- scale + diagonal mask ----
            float sv[4];
            #pragma unroll
            for (int r = 0; r < 4; ++r) sv[r] = (sc0[r] + sc1[r]) * 0.0625f;
            if (dmask) {
                #pragma unroll
                for (int r = 0; r < 4; ++r)
                    if (4 * g + r > c) sv[r] = -1e30f;
            }
            // ---- softmax: shuffle-free fast path ----
            float tm = fmaxf(fmaxf(sv[0], sv[1]), fmaxf(sv[2], sv[3]));
            if (!__all((int)(tm <= m + 8.f))) {          // rare slow path
                float tr = fmaxf(tm, __shfl_xor(tm, 16));
                tr = fmaxf(tr, __shfl_xor(tr, 32));
                float mnew = fmaxf(m, tr);
                float alpha = __expf(m - mnew);
                m = mnew;
                lsum *= alpha;
                #pragma unroll
                for (int i = 0; i < 16; ++i) acc[i] *= alpha;
            }
            float p[4];
            #pragma unroll
            for (int r = 0; r < 4; ++r) { p[r] = __expf(sv[r] - m); lsum += p[r]; }
            half4 pb;
            #pragma unroll
            for (int r = 0; r < 4; ++r) pb[r] = (_Float16)p[r];
            // ---- PV (16x16x16 f16) ----
            __builtin_amdgcn_s_setprio(1);
            #pragma unroll
            for (int vt = 0; vt < 16; ++vt) {
                half4 vf;
                #pragma unroll
                for (int jj = 0; jj < 4; ++jj) vf[jj] = vread[vt][sub * 4 + jj];
                acc[vt] = __builtin_amdgcn_mfma_f32_16x16x16f16(vf, pb, acc[vt], 0, 0, 0);
            }
            __builtin_amdgcn_s_setprio(0);
        }
    }

    // ---- epilogue: row-sum of lsum (only softmax shuffles), write ----
    lsum += __shfl_xor(lsum, 16);
    lsum += __shfl_xor(lsum, 32);
    float rl = 1.f / lsum;
    #pragma unroll
    for (int vt = 0; vt < 16; ++vt) {
        #pragma unroll
        for (int r = 0; r < 4; ++r)
            out[(((b << 8) + vt * 16 + 4 * g + r) << 10) + s0 + c] = acc[vt][r] * rl;
    }
}

// ---------- launcher ----------
extern "C" void kernel_launch(void* const* d_in, const int* in_sizes, int n_in,
                              void* d_out, int out_size, void* d_ws, size_t ws_size,
                              hipStream_t stream) {
    const float* x  = (const float*)d_in[0];
    const float* wq = (const float*)d_in[1];
    const float* bq = (const float*)d_in[2];
    const float* wk = (const float*)d_in[3];
    const float* bk = (const float*)d_in[4];
    const float* wv = (const float*)d_in[5];
    const float* bv = (const float*)d_in[6];
    float* out = (float*)d_out;

    char* ws = (char*)d_ws;
    unsigned short* Wb = (unsigned short*)ws;                       // 393,216 B
    unsigned short* Qb = (unsigned short*)(ws + 393216);
    unsigned short* Kb = (unsigned short*)(ws + 393216 + 16777216);
    _Float16*       Vb = (_Float16*)     (ws + 393216 + 2 * 16777216);
    unsigned short* PEt = (unsigned short*)(ws + 393216 + 3 * 16777216);

    wconv_kernel<<<769, 256, 0, stream>>>(wq, wk, wv, Wb, PEt);
    fproj_kernel<<<dim3(16, 32), 256, 0, stream>>>(x, Wb, PEt, bq, bk, bv, Qb, Kb, Vb);
    attn_kernel<<<512, 256, 0, stream>>>(Qb, Kb, Vb, out);
}